// Round 7
// baseline (334.081 us; speedup 1.0000x reference)
//
#include <hip/hip_runtime.h>
#include <hip/hip_bf16.h>

typedef float  f32x4 __attribute__((ext_vector_type(4)));
typedef short  s16x8 __attribute__((ext_vector_type(8)));

#define NB   1024
#define SEQ  64
#define DIM  512
#define NH   8
#define SCALE 0.044194173824159216f

// round-half-up f32->bf16: 2 VALU ops
static __device__ __forceinline__ unsigned short f2bf(float f) {
    unsigned u = __builtin_bit_cast(unsigned, f);
    return (unsigned short)((u + 0x8000u) >> 16);
}

static __device__ __forceinline__ f32x4 mma(s16x8 a, s16x8 b, f32x4 c) {
    return __builtin_amdgcn_mfma_f32_16x16x32_bf16(a, b, c, 0, 0, 0);
}

// load 8 consecutive f32, convert to a bf16 frag slice (fallback path)
static __device__ __forceinline__ s16x8 ldcvt(const float* p) {
    float4 v0 = *(const float4*)(p);
    float4 v1 = *(const float4*)(p + 4);
    s16x8 r;
    r[0] = (short)f2bf(v0.x); r[1] = (short)f2bf(v0.y);
    r[2] = (short)f2bf(v0.z); r[3] = (short)f2bf(v0.w);
    r[4] = (short)f2bf(v1.x); r[5] = (short)f2bf(v1.y);
    r[6] = (short)f2bf(v1.z); r[7] = (short)f2bf(v1.w);
    return r;
}

// Pre-kernel: Wq, Wc (f32 [512][512] row-major [k][n]) -> bf16 B-fragment order.
__global__ __launch_bounds__(256) void prep_weights(
    const float* __restrict__ Wq, const float* __restrict__ Wc,
    unsigned short* __restrict__ wf)
{
    int gid  = blockIdx.x * 256 + threadIdx.x;   // 0..65535
    int m    = gid >> 15;
    int tile = (gid >> 10) & 31;
    int ks   = (gid >> 6) & 15;
    int lane = gid & 63;
    const float* W = m ? Wc : Wq;
    int col = tile * 16 + (lane & 15);
    int k0  = ks * 32 + (lane >> 4) * 8;
    unsigned short* dst = wf + (size_t)gid * 8;
#pragma unroll
    for (int j = 0; j < 8; ++j)
        dst[j] = f2bf(W[(size_t)(k0 + j) * DIM + col]);
}

// ====================== Kernel 1: projections ======================
// One 512-thread block = one (b, m); 8 waves = 8 heads.
// 8 chunks of 64 cols (2 K-steps each), double-buffered 8KB LDS bufs.
// Per iter (T14 async-split): issue chunk c+1 loads -> regs; compute chunk c
// (ds_read + L2-hot weight frags + 32 MFMA/wave); cvt+ds_write c+1; barrier.
// LDS slot layout [kk][q][row]: slot%8 = row%8 -> conflict-free write & read.
__global__ __launch_bounds__(512, 4) void proj_kernel(
    const float* __restrict__ query,
    const float* __restrict__ context,
    const float* __restrict__ bq,
    const float* __restrict__ bc,
    const unsigned short* __restrict__ wf,
    unsigned short* __restrict__ pp)
{
    __shared__ unsigned short sA[2][4096];   // 2 x 512 slots x 16B = 16 KB

    const int tid  = threadIdx.x;
    const int lane = tid & 63;
    const int wv   = tid >> 6;        // wave id = head
    const int l15  = lane & 15;
    const int l4   = lane >> 4;

    // chunked swizzle: consecutive orig ids share an XCD for act L2 locality.
    const int i    = blockIdx.x;
    const int orig = (i & 7) * 256 + (i >> 3);
    const int b    = orig >> 1;
    const int m    = orig & 1;
    const int h    = wv;

    const float* act  = (m ? context : query) + (size_t)b * SEQ * DIM;
    const float* bias = m ? bc : bq;
    const unsigned short* wfm = wf + (size_t)m * 262144;

    // staging map: thread covers row=tid>>3, within-chunk cols (tid&7)*8..+7
    const int srow  = tid >> 3;
    const int scol  = (tid & 7) * 8;
    const int wslot = ((tid & 7) >> 2) * 256 + (tid & 3) * 64 + srow; // kk*256+q*64+row
    const float* srcbase = act + (size_t)srow * DIM + scol;

    const f32x4 fz = {0.f, 0.f, 0.f, 0.f};
    f32x4 acc[4][4];
#pragma unroll
    for (int x = 0; x < 4; ++x)
#pragma unroll
        for (int y = 0; y < 4; ++y) acc[x][y] = fz;

    // prologue: stage chunk 0
    float4 st0 = *(const float4*)(srcbase);
    float4 st1 = *(const float4*)(srcbase + 4);
    {
        s16x8 x;
        x[0] = (short)f2bf(st0.x); x[1] = (short)f2bf(st0.y);
        x[2] = (short)f2bf(st0.z); x[3] = (short)f2bf(st0.w);
        x[4] = (short)f2bf(st1.x); x[5] = (short)f2bf(st1.y);
        x[6] = (short)f2bf(st1.z); x[7] = (short)f2bf(st1.w);
        *(s16x8*)&sA[0][wslot * 8] = x;
    }
    __syncthreads();

#pragma unroll 2
    for (int c = 0; c < 8; ++c) {
        // (a) issue next chunk's global loads early
        if (c < 7) {
            const float* s = srcbase + (c + 1) * 64;
            st0 = *(const float4*)(s);
            st1 = *(const float4*)(s + 4);
        }
        // (b) compute current chunk: 2 K-steps
#pragma unroll
        for (int kk = 0; kk < 2; ++kk) {
            const int ksg = c * 2 + kk;
            s16x8 af[4], bf[4];
#pragma unroll
            for (int mt = 0; mt < 4; ++mt)
                af[mt] = *(const s16x8*)&sA[c & 1][(kk * 256 + l4 * 64 + mt * 16 + l15) * 8];
#pragma unroll
            for (int nt = 0; nt < 4; ++nt)
                bf[nt] = *(const s16x8*)(wfm +
                         ((size_t)((h * 4 + nt) * 16 + ksg) * 64 + lane) * 8);
#pragma unroll
            for (int mt = 0; mt < 4; ++mt)
#pragma unroll
                for (int nt = 0; nt < 4; ++nt)
                    acc[mt][nt] = mma(af[mt], bf[nt], acc[mt][nt]);
        }
        // (c) cvt + write staged chunk AFTER compute (wait lands here, hidden)
        if (c < 7) {
            s16x8 x;
            x[0] = (short)f2bf(st0.x); x[1] = (short)f2bf(st0.y);
            x[2] = (short)f2bf(st0.z); x[3] = (short)f2bf(st0.w);
            x[4] = (short)f2bf(st1.x); x[5] = (short)f2bf(st1.y);
            x[6] = (short)f2bf(st1.z); x[7] = (short)f2bf(st1.w);
            *(s16x8*)&sA[(c + 1) & 1][wslot * 8] = x;
        }
        __syncthreads();
    }

    unsigned short* dst = pp + (((size_t)m * NB + b) * NH + h) * 4096;
#pragma unroll
    for (int nt = 0; nt < 4; ++nt) {
        float bv = bias[h * 64 + nt * 16 + l15];
#pragma unroll
        for (int mt = 0; mt < 4; ++mt)
#pragma unroll
            for (int r = 0; r < 4; ++r)
                dst[(mt * 16 + l4 * 4 + r) * 64 + nt * 16 + l15] =
                    f2bf(acc[mt][nt][r] + bv);
    }
}

// ====================== Kernel 2: attention tail ======================
// One wave -> one (b,h). cb/qa as direct global frag loads; Qp staged in
// per-wave LDS only for the qb transpose; P1/P2^T reuse the same tile.
__global__ __launch_bounds__(256) void tail_kernel(
    const unsigned short* __restrict__ pp,
    float* __restrict__ out)
{
    __shared__ unsigned short sT[4][SEQ][72];

    const int lane = threadIdx.x & 63;
    const int wv   = threadIdx.x >> 6;
    const int l15  = lane & 15;
    const int l4   = lane >> 4;

    const int i    = blockIdx.x;
    const int orig = (i & 7) * 256 + (i >> 3);
    const int b    = orig >> 1;
    const int half = orig & 1;
    const int h    = half * 4 + wv;

    const unsigned short* qp = pp + ((size_t)b * NH + h) * 4096;
    const unsigned short* cp = pp + (((size_t)NB + b) * NH + h) * 4096;

    const f32x4 fz = {0.f, 0.f, 0.f, 0.f};
    unsigned short (*T)[72] = sT[wv];

    s16x8 cb[4][2], qa[4][2];
#pragma unroll
    for (int nt = 0; nt < 4; ++nt)
#pragma unroll
        for (int ks = 0; ks < 2; ++ks)
            cb[nt][ks] = *(const s16x8*)(cp + (nt * 16 + l15) * 64 + ks * 32 + l4 * 8);
#pragma unroll
    for (int mt = 0; mt < 4; ++mt)
#pragma unroll
        for (int ks = 0; ks < 2; ++ks)
            qa[mt][ks] = *(const s16x8*)(qp + (mt * 16 + l15) * 64 + ks * 32 + l4 * 8);

#pragma unroll
    for (int j = 0; j < 8; ++j) {
        int row = j * 8 + (lane >> 3);
        int col = (lane & 7) * 8;
        *(s16x8*)&T[row][col] = *(const s16x8*)(qp + row * 64 + col);
    }

    s16x8 qb[4][2];
#pragma unroll
    for (int nt = 0; nt < 4; ++nt)
#pragma unroll
        for (int ks = 0; ks < 2; ++ks) {
            s16x8 v;
#pragma unroll
            for (int j = 0; j < 8; ++j)
                v[j] = (short)T[ks * 32 + l4 * 8 + j][nt * 16 + l15];
            qb[nt][ks] = v;
        }

    f32x4 Sc[4][4];
#pragma unroll
    for (int x = 0; x < 4; ++x)
#pragma unroll
        for (int y = 0; y < 4; ++y) Sc[x][y] = fz;
#pragma unroll
    for (int ks = 0; ks < 2; ++ks)
#pragma unroll
        for (int mt = 0; mt < 4; ++mt)
#pragma unroll
            for (int nt = 0; nt < 4; ++nt)
                Sc[mt][nt] = mma(qa[mt][ks], cb[nt][ks], Sc[mt][nt]);

    // softmax over keys (rows): P1 -> T
#pragma unroll
    for (int mt = 0; mt < 4; ++mt)
#pragma unroll
        for (int r = 0; r < 4; ++r) {
            float m = fmaxf(fmaxf(Sc[mt][0][r], Sc[mt][1][r]),
                            fmaxf(Sc[mt][2][r], Sc[mt][3][r]));
            m = fmaxf(m, __shfl_xor(m, 1));
            m = fmaxf(m, __shfl_xor(m, 2));
            m = fmaxf(m, __shfl_xor(m, 4));
            m = fmaxf(m, __shfl_xor(m, 8));
            float e[4], s = 0.f;
#pragma unroll
            for (int nt = 0; nt < 4; ++nt) { e[nt] = __expf(SCALE * (Sc[mt][nt][r] - m)); s += e[nt]; }
            s += __shfl_xor(s, 1);
            s += __shfl_xor(s, 2);
            s += __shfl_xor(s, 4);
            s += __shfl_xor(s, 8);
            float inv = 1.f / s;
            int row = mt * 16 + l4 * 4 + r;
#pragma unroll
            for (int nt = 0; nt < 4; ++nt)
                T[row][nt * 16 + l15] = f2bf(e[nt] * inv);
        }

    s16x8 pa[4][2];
#pragma unroll
    for (int mt = 0; mt < 4; ++mt)
#pragma unroll
        for (int ks = 0; ks < 2; ++ks)
            pa[mt][ks] = *(const s16x8*)&T[mt * 16 + l15][ks * 32 + l4 * 8];

    // softmax over queries (cols): P2^T -> T
#pragma unroll
    for (int nt = 0; nt < 4; ++nt) {
        float m = -1e30f;
#pragma unroll
        for (int mt = 0; mt < 4; ++mt)
#pragma unroll
            for (int r = 0; r < 4; ++r) m = fmaxf(m, Sc[mt][nt][r]);
        m = fmaxf(m, __shfl_xor(m, 16));
        m = fmaxf(m, __shfl_xor(m, 32));
        float ee[4][4], s = 0.f;
#pragma unroll
        for (int mt = 0; mt < 4; ++mt)
#pragma unroll
            for (int r = 0; r < 4; ++r) { ee[mt][r] = __expf(SCALE * (Sc[mt][nt][r] - m)); s += ee[mt][r]; }
        s += __shfl_xor(s, 16);
        s += __shfl_xor(s, 32);
        float inv = 1.f / s;
        int krow = nt * 16 + l15;
#pragma unroll
        for (int mt = 0; mt < 4; ++mt)
#pragma unroll
            for (int r = 0; r < 4; ++r)
                T[krow][mt * 16 + l4 * 4 + r] = f2bf(ee[mt][r] * inv);
    }

    // c_coattn = P1 @ Cp^T
    f32x4 O[4][4];
#pragma unroll
    for (int x = 0; x < 4; ++x)
#pragma unroll
        for (int y = 0; y < 4; ++y) O[x][y] = fz;
#pragma unroll
    for (int ks = 0; ks < 2; ++ks)
#pragma unroll
        for (int mt = 0; mt < 4; ++mt)
#pragma unroll
            for (int nt = 0; nt < 4; ++nt)
                O[mt][nt] = mma(pa[mt][ks], cb[nt][ks], O[mt][nt]);

    float* cO = out;
#pragma unroll
    for (int mt = 0; mt < 4; ++mt)
#pragma unroll
        for (int nt = 0; nt < 4; ++nt)
#pragma unroll
            for (int r = 0; r < 4; ++r) {
                int qrow = mt * 16 + l4 * 4 + r;
                cO[((size_t)b * SEQ + qrow) * (NH * 64) + h * 64 + nt * 16 + l15] = O[mt][nt][r];
            }

    // q_coattn = P2^T @ Qp
    s16x8 p2a[4][2];
#pragma unroll
    for (int mt = 0; mt < 4; ++mt)
#pragma unroll
        for (int ks = 0; ks < 2; ++ks)
            p2a[mt][ks] = *(const s16x8*)&T[mt * 16 + l15][ks * 32 + l4 * 8];

#pragma unroll
    for (int x = 0; x < 4; ++x)
#pragma unroll
        for (int y = 0; y < 4; ++y) O[x][y] = fz;
#pragma unroll
    for (int ks = 0; ks < 2; ++ks)
#pragma unroll
        for (int mt = 0; mt < 4; ++mt)
#pragma unroll
            for (int nt = 0; nt < 4; ++nt)
                O[mt][nt] = mma(p2a[mt][ks], qb[nt][ks], O[mt][nt]);

    float* qO = out + (size_t)NB * SEQ * NH * 64;
#pragma unroll
    for (int mt = 0; mt < 4; ++mt)
#pragma unroll
        for (int nt = 0; nt < 4; ++nt)
#pragma unroll
            for (int r = 0; r < 4; ++r) {
                int krow = mt * 16 + l4 * 4 + r;
                qO[((size_t)b * SEQ + krow) * (NH * 64) + h * 64 + nt * 16 + l15] = O[mt][nt][r];
            }
}

// ====================== Fallback: fused (round-3 style) ======================
__global__ __launch_bounds__(256) void coattn_fused(
    const float* __restrict__ query,
    const float* __restrict__ context,
    const float* __restrict__ bq,
    const float* __restrict__ bc,
    const unsigned short* __restrict__ wf,
    float* __restrict__ out)
{
    __shared__ unsigned short sT[4][SEQ][72];
    const int tid  = threadIdx.x;
    const int lane = tid & 63;
    const int wv   = tid >> 6;
    const int l15  = lane & 15;
    const int l4   = lane >> 4;
    const int B_id = blockIdx.x;
    const int half = (B_id >> 3) & 1;
    const int b    = (B_id & 7) | ((B_id >> 4) << 3);
    const int h    = half * 4 + wv;
    const float* gq = query   + (size_t)b * SEQ * DIM;
    const float* gc = context + (size_t)b * SEQ * DIM;
    const f32x4 fz = {0.f, 0.f, 0.f, 0.f};
    unsigned short (*T)[72] = sT[wv];
    f32x4 acc[4][4];
#pragma unroll
    for (int i = 0; i < 4; ++i)
#pragma unroll
        for (int j = 0; j < 4; ++j) acc[i][j] = fz;
    for (int ks = 0; ks < 16; ++ks) {
        const int k0 = ks * 32 + l4 * 8;
        s16x8 af[4], bf[4];
#pragma unroll
        for (int mt = 0; mt < 4; ++mt)
            af[mt] = ldcvt(gc + (size_t)(mt * 16 + l15) * DIM + k0);
#pragma unroll
        for (int nt = 0; nt < 4; ++nt)
            bf[nt] = *(const s16x8*)(wf + 262144 +
                     ((size_t)((h * 4 + nt) * 16 + ks) * 64 + lane) * 8);
#pragma unroll
        for (int mt = 0; mt < 4; ++mt)
#pragma unroll
            for (int nt = 0; nt < 4; ++nt)
                acc[mt][nt] = mma(af[mt], bf[nt], acc[mt][nt]);
    }
#pragma unroll
    for (int nt = 0; nt < 4; ++nt) {
        float bcv = bc[h * 64 + nt * 16 + l15];
#pragma unroll
        for (int mt = 0; mt < 4; ++mt)
#pragma unroll
            for (int r = 0; r < 4; ++r)
                T[mt * 16 + l4 * 4 + r][nt * 16 + l15] = f2bf(acc[mt][nt][r] + bcv);
    }
    s16x8 cb[4][2];
#pragma unroll
    for (int nt = 0; nt < 4; ++nt)
#pragma unroll
        for (int ks = 0; ks < 2; ++ks)
            cb[nt][ks] = *(const s16x8*)&T[nt * 16 + l15][ks * 32 + l4 * 8];
#pragma unroll
    for (int i = 0; i < 4; ++i)
#pragma unroll
        for (int j = 0; j < 4; ++j) acc[i][j] = fz;
    for (int ks = 0; ks < 16; ++ks) {
        const int k0 = ks * 32 + l4 * 8;
        s16x8 af[4], bf[4];
#pragma unroll
        for (int mt = 0; mt < 4; ++mt)
            af[mt] = ldcvt(gq + (size_t)(mt * 16 + l15) * DIM + k0);
#pragma unroll
        for (int nt = 0; nt < 4; ++nt)
            bf[nt] = *(const s16x8*)(wf +
                     ((size_t)((h * 4 + nt) * 16 + ks) * 64 + lane) * 8);
#pragma unroll
        for (int mt = 0; mt < 4; ++mt)
#pragma unroll
            for (int nt = 0; nt < 4; ++nt)
                acc[mt][nt] = mma(af[mt], bf[nt], acc[mt][nt]);
    }
#pragma unroll
    for (int nt = 0; nt < 4; ++nt) {
        float bqv = bq[h * 64 + nt * 16 + l15];
#pragma unroll
        for (int mt = 0; mt < 4; ++mt)
#pragma unroll
            for (int r = 0; r < 4; ++r)
                T[mt * 16 + l4 * 4 + r][nt * 16 + l15] = f2bf(acc[mt][nt][r] + bqv);
    }
    s16x8 qa[4][2], qb[4][2];
#pragma unroll
    for (int mt = 0; mt < 4; ++mt)
#pragma unroll
        for (int ks = 0; ks < 2; ++ks)
            qa[mt][ks] = *(const s16x8*)&T[mt * 16 + l15][ks * 32 + l4 * 8];
#pragma unroll
    for (int nt = 0; nt < 4; ++nt)
#pragma unroll
        for (int ks = 0; ks < 2; ++ks) {
            s16x8 v;
#pragma unroll
            for (int j = 0; j < 8; ++j)
                v[j] = (short)T[ks * 32 + l4 * 8 + j][nt * 16 + l15];
            qb[nt][ks] = v;
        }
    f32x4 Sc[4][4];
#pragma unroll
    for (int i = 0; i < 4; ++i)
#pragma unroll
        for (int j = 0; j < 4; ++j) Sc[i][j] = fz;
#pragma unroll
    for (int ks = 0; ks < 2; ++ks)
#pragma unroll
        for (int mt = 0; mt < 4; ++mt)
#pragma unroll
            for (int nt = 0; nt < 4; ++nt)
                Sc[mt][nt] = mma(qa[mt][ks], cb[nt][ks], Sc[mt][nt]);
#pragma unroll
    for (int mt = 0; mt < 4; ++mt)
#pragma unroll
        for (int r = 0; r < 4; ++r) {
            float m = fmaxf(fmaxf(Sc[mt][0][r], Sc[mt][1][r]),
                            fmaxf(Sc[mt][2][r], Sc[mt][3][r]));
            m = fmaxf(m, __shfl_xor(m, 1));
            m = fmaxf(m, __shfl_xor(m, 2));
            m = fmaxf(m, __shfl_xor(m, 4));
            m = fmaxf(m, __shfl_xor(m, 8));
            float e[4], s = 0.f;
#pragma unroll
            for (int nt = 0; nt < 4; ++nt) { e[nt] = __expf(SCALE * (Sc[mt][nt][r] - m)); s += e[nt]; }
            s += __shfl_xor(s, 1);
            s += __shfl_xor(s, 2);
            s += __shfl_xor(s, 4);
            s += __shfl_xor(s, 8);
            float inv = 1.f / s;
            int row = mt * 16 + l4 * 4 + r;
#pragma unroll
            for (int nt = 0; nt < 4; ++nt)
                T[row][nt * 16 + l15] = f2bf(e[nt] * inv);
        }
    s16x8 pa[4][2];
#pragma unroll
    for (int mt = 0; mt < 4; ++mt)
#pragma unroll
        for (int ks = 0; ks < 2; ++ks)
            pa[mt][ks] = *(const s16x8*)&T[mt * 16 + l15][ks * 32 + l4 * 8];
#pragma unroll
    for (int nt = 0; nt < 4; ++nt) {
        float m = -1e30f;
#pragma unroll
        for (int mt = 0; mt < 4; ++mt)
#pragma unroll
            for (int r = 0; r < 4; ++r) m = fmaxf(m, Sc[mt][nt][r]);
        m = fmaxf(m, __shfl_xor(m, 16));
        m = fmaxf(m, __shfl_xor(m, 32));
        float ee[4][4], s = 0.f;
#pragma unroll
        for (int mt = 0; mt < 4; ++mt)
#pragma unroll
            for (int r = 0; r < 4; ++r) { ee[mt][r] = __expf(SCALE * (Sc[mt][nt][r] - m)); s += ee[mt][r]; }
        s += __shfl_xor(s, 16);
        s += __shfl_xor(s, 32);
        float inv = 1.f / s;
        int krow = nt * 16 + l15;
#pragma unroll
        for (int mt = 0; mt < 4; ++mt)
#pragma unroll
            for (int r = 0; r < 4; ++r)
                T[krow][mt * 16 + l4 * 4 + r] = f2bf(ee[mt][r] * inv);
    }
    s16x8 p2a[4][2];
#pragma unroll
    for (int mt = 0; mt < 4; ++mt)
#pragma unroll
        for (int ks = 0; ks < 2; ++ks)
            p2a[mt][ks] = *(const s16x8*)&T[mt * 16 + l15][ks * 32 + l4 * 8];
    f32x4 O[4][4];
#pragma unroll
    for (int i = 0; i < 4; ++i)
#pragma unroll
        for (int j = 0; j < 4; ++j) O[i][j] = fz;
#pragma unroll
    for (int ks = 0; ks < 2; ++ks)
#pragma unroll
        for (int mt = 0; mt < 4; ++mt)
#pragma unroll
            for (int nt = 0; nt < 4; ++nt)
                O[mt][nt] = mma(pa[mt][ks], cb[nt][ks], O[mt][nt]);
    float* cO = out;
#pragma unroll
    for (int mt = 0; mt < 4; ++mt)
#pragma unroll
        for (int nt = 0; nt < 4; ++nt)
#pragma unroll
            for (int r = 0; r < 4; ++r) {
                int qrow = mt * 16 + l4 * 4 + r;
                cO[((size_t)b * SEQ + qrow) * (NH * 64) + h * 64 + nt * 16 + l15] = O[mt][nt][r];
            }
#pragma unroll
    for (int i = 0; i < 4; ++i)
#pragma unroll
        for (int j = 0; j < 4; ++j) O[i][j] = fz;
#pragma unroll
    for (int ks = 0; ks < 2; ++ks)
#pragma unroll
        for (int mt = 0; mt < 4; ++mt)
#pragma unroll
            for (int nt = 0; nt < 4; ++nt)
                O[mt][nt] = mma(p2a[mt][ks], qb[nt][ks], O[mt][nt]);
    float* qO = out + (size_t)NB * SEQ * NH * 64;
#pragma unroll
    for (int mt = 0; mt < 4; ++mt)
#pragma unroll
        for (int nt = 0; nt < 4; ++nt)
#pragma unroll
            for (int r = 0; r < 4; ++r) {
                int krow = mt * 16 + l4 * 4 + r;
                qO[((size_t)b * SEQ + krow) * (NH * 64) + h * 64 + nt * 16 + l15] = O[mt][nt][r];
            }
}

extern "C" void kernel_launch(void* const* d_in, const int* in_sizes, int n_in,
                              void* d_out, int out_size, void* d_ws, size_t ws_size,
                              hipStream_t stream) {
    const float* query   = (const float*)d_in[0];
    const float* context = (const float*)d_in[1];
    const float* Wq      = (const float*)d_in[2];
    const float* bq      = (const float*)d_in[3];
    const float* Wc      = (const float*)d_in[4];
    const float* bc      = (const float*)d_in[5];
    float* out = (float*)d_out;

    unsigned short* wfrag = (unsigned short*)d_ws;            // 1 MB
    unsigned short* pp    = wfrag + 524288;                   // 134.2 MB
    const size_t need = (524288 + (size_t)2 * NB * NH * 4096) * sizeof(unsigned short);

    prep_weights<<<256, 256, 0, stream>>>(Wq, Wc, wfrag);
    if (ws_size >= need) {
        proj_kernel<<<2048, 512, 0, stream>>>(query, context, bq, bc, wfrag, pp);
        tail_kernel<<<2048, 256, 0, stream>>>(pp, out);
    } else {
        coattn_fused<<<NB * 2, 256, 0, stream>>>(query, context, bq, bc, wfrag, out);
    }
}

// Round 8
// 290.315 us; speedup vs baseline: 1.1508x; 1.1508x over previous
//
#include <hip/hip_runtime.h>
#include <hip/hip_bf16.h>

typedef float  f32x4 __attribute__((ext_vector_type(4)));
typedef short  s16x8 __attribute__((ext_vector_type(8)));

#define NB   1024
#define SEQ  64
#define DIM  512
#define NH   8
#define SCALE 0.044194173824159216f

// round-half-up f32->bf16: 2 VALU ops
static __device__ __forceinline__ unsigned short f2bf(float f) {
    unsigned u = __builtin_bit_cast(unsigned, f);
    return (unsigned short)((u + 0x8000u) >> 16);
}

static __device__ __forceinline__ f32x4 mma(s16x8 a, s16x8 b, f32x4 c) {
    return __builtin_amdgcn_mfma_f32_16x16x32_bf16(a, b, c, 0, 0, 0);
}

// load 8 consecutive f32, convert to a bf16 frag slice (fallback path)
static __device__ __forceinline__ s16x8 ldcvt(const float* p) {
    float4 v0 = *(const float4*)(p);
    float4 v1 = *(const float4*)(p + 4);
    s16x8 r;
    r[0] = (short)f2bf(v0.x); r[1] = (short)f2bf(v0.y);
    r[2] = (short)f2bf(v0.z); r[3] = (short)f2bf(v0.w);
    r[4] = (short)f2bf(v1.x); r[5] = (short)f2bf(v1.y);
    r[6] = (short)f2bf(v1.z); r[7] = (short)f2bf(v1.w);
    return r;
}

// Pre-kernel: Wq, Wc (f32 [512][512] row-major [k][n]) -> bf16 B-fragment order.
__global__ __launch_bounds__(256) void prep_weights(
    const float* __restrict__ Wq, const float* __restrict__ Wc,
    unsigned short* __restrict__ wf)
{
    int gid  = blockIdx.x * 256 + threadIdx.x;   // 0..65535
    int m    = gid >> 15;
    int tile = (gid >> 10) & 31;
    int ks   = (gid >> 6) & 15;
    int lane = gid & 63;
    const float* W = m ? Wc : Wq;
    int col = tile * 16 + (lane & 15);
    int k0  = ks * 32 + (lane >> 4) * 8;
    unsigned short* dst = wf + (size_t)gid * 8;
#pragma unroll
    for (int j = 0; j < 8; ++j)
        dst[j] = f2bf(W[(size_t)(k0 + j) * DIM + col]);
}

// ====================== Kernel 1: projections ======================
// One 512-thread block = one (b, m); 8 waves = 8 heads.
// 8 chunks of 64 cols (2 K-steps each), double-buffered 8KB LDS bufs.
// Per iter (T14 async-split): issue chunk c+1 loads -> regs; compute chunk c
// (ds_read + L2-hot weight frags + 32 MFMA/wave); cvt+ds_write c+1; barrier.
// LDS slot layout [kk][q][row]: slot%8 = row%8 -> both ds_write_b128 and
// ds_read_b128 hit the 8-phase minimum (conflict-free).
// NOTE: plain __launch_bounds__(512) — a min-waves 2nd arg clamps the unified
// VGPR/AGPR budget below the 64-AGPR accumulator and forces scratch spills
// (proved twice: round 2 and round 7; WRITE_SIZE +100 MB both times).
__global__ __launch_bounds__(512) void proj_kernel(
    const float* __restrict__ query,
    const float* __restrict__ context,
    const float* __restrict__ bq,
    const float* __restrict__ bc,
    const unsigned short* __restrict__ wf,
    unsigned short* __restrict__ pp)
{
    __shared__ unsigned short sA[2][4096];   // 2 x 512 slots x 16B = 16 KB

    const int tid  = threadIdx.x;
    const int lane = tid & 63;
    const int wv   = tid >> 6;        // wave id = head
    const int l15  = lane & 15;
    const int l4   = lane >> 4;

    // chunked swizzle: consecutive orig ids share an XCD for act L2 locality.
    const int i    = blockIdx.x;
    const int orig = (i & 7) * 256 + (i >> 3);
    const int b    = orig >> 1;
    const int m    = orig & 1;
    const int h    = wv;

    const float* act  = (m ? context : query) + (size_t)b * SEQ * DIM;
    const float* bias = m ? bc : bq;
    const unsigned short* wfm = wf + (size_t)m * 262144;

    // staging map: thread covers row=tid>>3, within-chunk cols (tid&7)*8..+7
    const int srow  = tid >> 3;
    const int wslot = ((tid & 7) >> 2) * 256 + (tid & 3) * 64 + srow; // kk*256+q*64+row
    const float* srcbase = act + (size_t)srow * DIM + (tid & 7) * 8;

    const f32x4 fz = {0.f, 0.f, 0.f, 0.f};
    f32x4 acc[4][4];
#pragma unroll
    for (int x = 0; x < 4; ++x)
#pragma unroll
        for (int y = 0; y < 4; ++y) acc[x][y] = fz;

    // prologue: stage chunk 0
    float4 st0 = *(const float4*)(srcbase);
    float4 st1 = *(const float4*)(srcbase + 4);
    {
        s16x8 x;
        x[0] = (short)f2bf(st0.x); x[1] = (short)f2bf(st0.y);
        x[2] = (short)f2bf(st0.z); x[3] = (short)f2bf(st0.w);
        x[4] = (short)f2bf(st1.x); x[5] = (short)f2bf(st1.y);
        x[6] = (short)f2bf(st1.z); x[7] = (short)f2bf(st1.w);
        *(s16x8*)&sA[0][wslot * 8] = x;
    }
    __syncthreads();

#pragma unroll 2
    for (int c = 0; c < 8; ++c) {
        // (a) issue next chunk's global loads early
        if (c < 7) {
            const float* s = srcbase + (c + 1) * 64;
            st0 = *(const float4*)(s);
            st1 = *(const float4*)(s + 4);
        }
        // (b) compute current chunk: 2 K-steps
#pragma unroll
        for (int kk = 0; kk < 2; ++kk) {
            const int ksg = c * 2 + kk;
            s16x8 af[4], bf[4];
#pragma unroll
            for (int mt = 0; mt < 4; ++mt)
                af[mt] = *(const s16x8*)&sA[c & 1][(kk * 256 + l4 * 64 + mt * 16 + l15) * 8];
#pragma unroll
            for (int nt = 0; nt < 4; ++nt)
                bf[nt] = *(const s16x8*)(wfm +
                         ((size_t)((h * 4 + nt) * 16 + ksg) * 64 + lane) * 8);
#pragma unroll
            for (int mt = 0; mt < 4; ++mt)
#pragma unroll
                for (int nt = 0; nt < 4; ++nt)
                    acc[mt][nt] = mma(af[mt], bf[nt], acc[mt][nt]);
        }
        // (c) cvt + write staged chunk AFTER compute (wait lands here, hidden)
        if (c < 7) {
            s16x8 x;
            x[0] = (short)f2bf(st0.x); x[1] = (short)f2bf(st0.y);
            x[2] = (short)f2bf(st0.z); x[3] = (short)f2bf(st0.w);
            x[4] = (short)f2bf(st1.x); x[5] = (short)f2bf(st1.y);
            x[6] = (short)f2bf(st1.z); x[7] = (short)f2bf(st1.w);
            *(s16x8*)&sA[(c + 1) & 1][wslot * 8] = x;
        }
        __syncthreads();
    }

    unsigned short* dst = pp + (((size_t)m * NB + b) * NH + h) * 4096;
#pragma unroll
    for (int nt = 0; nt < 4; ++nt) {
        float bv = bias[h * 64 + nt * 16 + l15];
#pragma unroll
        for (int mt = 0; mt < 4; ++mt)
#pragma unroll
            for (int r = 0; r < 4; ++r)
                dst[(mt * 16 + l4 * 4 + r) * 64 + nt * 16 + l15] =
                    f2bf(acc[mt][nt][r] + bv);
    }
}

// ====================== Kernel 2: attention tail ======================
// One wave -> one (b,h). cb/qa as direct global frag loads; Qp staged in
// per-wave LDS only for the qb transpose; P1/P2^T reuse the same tile.
__global__ __launch_bounds__(256) void tail_kernel(
    const unsigned short* __restrict__ pp,
    float* __restrict__ out)
{
    __shared__ unsigned short sT[4][SEQ][72];

    const int lane = threadIdx.x & 63;
    const int wv   = threadIdx.x >> 6;
    const int l15  = lane & 15;
    const int l4   = lane >> 4;

    const int i    = blockIdx.x;
    const int orig = (i & 7) * 256 + (i >> 3);
    const int b    = orig >> 1;
    const int half = orig & 1;
    const int h    = half * 4 + wv;

    const unsigned short* qp = pp + ((size_t)b * NH + h) * 4096;
    const unsigned short* cp = pp + (((size_t)NB + b) * NH + h) * 4096;

    const f32x4 fz = {0.f, 0.f, 0.f, 0.f};
    unsigned short (*T)[72] = sT[wv];

    s16x8 cb[4][2], qa[4][2];
#pragma unroll
    for (int nt = 0; nt < 4; ++nt)
#pragma unroll
        for (int ks = 0; ks < 2; ++ks)
            cb[nt][ks] = *(const s16x8*)(cp + (nt * 16 + l15) * 64 + ks * 32 + l4 * 8);
#pragma unroll
    for (int mt = 0; mt < 4; ++mt)
#pragma unroll
        for (int ks = 0; ks < 2; ++ks)
            qa[mt][ks] = *(const s16x8*)(qp + (mt * 16 + l15) * 64 + ks * 32 + l4 * 8);

#pragma unroll
    for (int j = 0; j < 8; ++j) {
        int row = j * 8 + (lane >> 3);
        int col = (lane & 7) * 8;
        *(s16x8*)&T[row][col] = *(const s16x8*)(qp + row * 64 + col);
    }

    s16x8 qb[4][2];
#pragma unroll
    for (int nt = 0; nt < 4; ++nt)
#pragma unroll
        for (int ks = 0; ks < 2; ++ks) {
            s16x8 v;
#pragma unroll
            for (int j = 0; j < 8; ++j)
                v[j] = (short)T[ks * 32 + l4 * 8 + j][nt * 16 + l15];
            qb[nt][ks] = v;
        }

    f32x4 Sc[4][4];
#pragma unroll
    for (int x = 0; x < 4; ++x)
#pragma unroll
        for (int y = 0; y < 4; ++y) Sc[x][y] = fz;
#pragma unroll
    for (int ks = 0; ks < 2; ++ks)
#pragma unroll
        for (int mt = 0; mt < 4; ++mt)
#pragma unroll
            for (int nt = 0; nt < 4; ++nt)
                Sc[mt][nt] = mma(qa[mt][ks], cb[nt][ks], Sc[mt][nt]);

    // softmax over keys (rows): P1 -> T
#pragma unroll
    for (int mt = 0; mt < 4; ++mt)
#pragma unroll
        for (int r = 0; r < 4; ++r) {
            float m = fmaxf(fmaxf(Sc[mt][0][r], Sc[mt][1][r]),
                            fmaxf(Sc[mt][2][r], Sc[mt][3][r]));
            m = fmaxf(m, __shfl_xor(m, 1));
            m = fmaxf(m, __shfl_xor(m, 2));
            m = fmaxf(m, __shfl_xor(m, 4));
            m = fmaxf(m, __shfl_xor(m, 8));
            float e[4], s = 0.f;
#pragma unroll
            for (int nt = 0; nt < 4; ++nt) { e[nt] = __expf(SCALE * (Sc[mt][nt][r] - m)); s += e[nt]; }
            s += __shfl_xor(s, 1);
            s += __shfl_xor(s, 2);
            s += __shfl_xor(s, 4);
            s += __shfl_xor(s, 8);
            float inv = 1.f / s;
            int row = mt * 16 + l4 * 4 + r;
#pragma unroll
            for (int nt = 0; nt < 4; ++nt)
                T[row][nt * 16 + l15] = f2bf(e[nt] * inv);
        }

    s16x8 pa[4][2];
#pragma unroll
    for (int mt = 0; mt < 4; ++mt)
#pragma unroll
        for (int ks = 0; ks < 2; ++ks)
            pa[mt][ks] = *(const s16x8*)&T[mt * 16 + l15][ks * 32 + l4 * 8];

    // softmax over queries (cols): P2^T -> T
#pragma unroll
    for (int nt = 0; nt < 4; ++nt) {
        float m = -1e30f;
#pragma unroll
        for (int mt = 0; mt < 4; ++mt)
#pragma unroll
            for (int r = 0; r < 4; ++r) m = fmaxf(m, Sc[mt][nt][r]);
        m = fmaxf(m, __shfl_xor(m, 16));
        m = fmaxf(m, __shfl_xor(m, 32));
        float ee[4][4], s = 0.f;
#pragma unroll
        for (int mt = 0; mt < 4; ++mt)
#pragma unroll
            for (int r = 0; r < 4; ++r) { ee[mt][r] = __expf(SCALE * (Sc[mt][nt][r] - m)); s += ee[mt][r]; }
        s += __shfl_xor(s, 16);
        s += __shfl_xor(s, 32);
        float inv = 1.f / s;
        int krow = nt * 16 + l15;
#pragma unroll
        for (int mt = 0; mt < 4; ++mt)
#pragma unroll
            for (int r = 0; r < 4; ++r)
                T[krow][mt * 16 + l4 * 4 + r] = f2bf(ee[mt][r] * inv);
    }

    // c_coattn = P1 @ Cp^T
    f32x4 O[4][4];
#pragma unroll
    for (int x = 0; x < 4; ++x)
#pragma unroll
        for (int y = 0; y < 4; ++y) O[x][y] = fz;
#pragma unroll
    for (int ks = 0; ks < 2; ++ks)
#pragma unroll
        for (int mt = 0; mt < 4; ++mt)
#pragma unroll
            for (int nt = 0; nt < 4; ++nt)
                O[mt][nt] = mma(pa[mt][ks], cb[nt][ks], O[mt][nt]);

    float* cO = out;
#pragma unroll
    for (int mt = 0; mt < 4; ++mt)
#pragma unroll
        for (int nt = 0; nt < 4; ++nt)
#pragma unroll
            for (int r = 0; r < 4; ++r) {
                int qrow = mt * 16 + l4 * 4 + r;
                cO[((size_t)b * SEQ + qrow) * (NH * 64) + h * 64 + nt * 16 + l15] = O[mt][nt][r];
            }

    // q_coattn = P2^T @ Qp
    s16x8 p2a[4][2];
#pragma unroll
    for (int mt = 0; mt < 4; ++mt)
#pragma unroll
        for (int ks = 0; ks < 2; ++ks)
            p2a[mt][ks] = *(const s16x8*)&T[mt * 16 + l15][ks * 32 + l4 * 8];

#pragma unroll
    for (int x = 0; x < 4; ++x)
#pragma unroll
        for (int y = 0; y < 4; ++y) O[x][y] = fz;
#pragma unroll
    for (int ks = 0; ks < 2; ++ks)
#pragma unroll
        for (int mt = 0; mt < 4; ++mt)
#pragma unroll
            for (int nt = 0; nt < 4; ++nt)
                O[mt][nt] = mma(p2a[mt][ks], qb[nt][ks], O[mt][nt]);

    float* qO = out + (size_t)NB * SEQ * NH * 64;
#pragma unroll
    for (int mt = 0; mt < 4; ++mt)
#pragma unroll
        for (int nt = 0; nt < 4; ++nt)
#pragma unroll
            for (int r = 0; r < 4; ++r) {
                int krow = mt * 16 + l4 * 4 + r;
                qO[((size_t)b * SEQ + krow) * (NH * 64) + h * 64 + nt * 16 + l15] = O[mt][nt][r];
            }
}

// ====================== Fallback: fused (round-3 style) ======================
__global__ __launch_bounds__(256) void coattn_fused(
    const float* __restrict__ query,
    const float* __restrict__ context,
    const float* __restrict__ bq,
    const float* __restrict__ bc,
    const unsigned short* __restrict__ wf,
    float* __restrict__ out)
{
    __shared__ unsigned short sT[4][SEQ][72];
    const int tid  = threadIdx.x;
    const int lane = tid & 63;
    const int wv   = tid >> 6;
    const int l15  = lane & 15;
    const int l4   = lane >> 4;
    const int B_id = blockIdx.x;
    const int half = (B_id >> 3) & 1;
    const int b    = (B_id & 7) | ((B_id >> 4) << 3);
    const int h    = half * 4 + wv;
    const float* gq = query   + (size_t)b * SEQ * DIM;
    const float* gc = context + (size_t)b * SEQ * DIM;
    const f32x4 fz = {0.f, 0.f, 0.f, 0.f};
    unsigned short (*T)[72] = sT[wv];
    f32x4 acc[4][4];
#pragma unroll
    for (int i = 0; i < 4; ++i)
#pragma unroll
        for (int j = 0; j < 4; ++j) acc[i][j] = fz;
    for (int ks = 0; ks < 16; ++ks) {
        const int k0 = ks * 32 + l4 * 8;
        s16x8 af[4], bf[4];
#pragma unroll
        for (int mt = 0; mt < 4; ++mt)
            af[mt] = ldcvt(gc + (size_t)(mt * 16 + l15) * DIM + k0);
#pragma unroll
        for (int nt = 0; nt < 4; ++nt)
            bf[nt] = *(const s16x8*)(wf + 262144 +
                     ((size_t)((h * 4 + nt) * 16 + ks) * 64 + lane) * 8);
#pragma unroll
        for (int mt = 0; mt < 4; ++mt)
#pragma unroll
            for (int nt = 0; nt < 4; ++nt)
                acc[mt][nt] = mma(af[mt], bf[nt], acc[mt][nt]);
    }
#pragma unroll
    for (int nt = 0; nt < 4; ++nt) {
        float bcv = bc[h * 64 + nt * 16 + l15];
#pragma unroll
        for (int mt = 0; mt < 4; ++mt)
#pragma unroll
            for (int r = 0; r < 4; ++r)
                T[mt * 16 + l4 * 4 + r][nt * 16 + l15] = f2bf(acc[mt][nt][r] + bcv);
    }
    s16x8 cb[4][2];
#pragma unroll
    for (int nt = 0; nt < 4; ++nt)
#pragma unroll
        for (int ks = 0; ks < 2; ++ks)
            cb[nt][ks] = *(const s16x8*)&T[nt * 16 + l15][ks * 32 + l4 * 8];
#pragma unroll
    for (int i = 0; i < 4; ++i)
#pragma unroll
        for (int j = 0; j < 4; ++j) acc[i][j] = fz;
    for (int ks = 0; ks < 16; ++ks) {
        const int k0 = ks * 32 + l4 * 8;
        s16x8 af[4], bf[4];
#pragma unroll
        for (int mt = 0; mt < 4; ++mt)
            af[mt] = ldcvt(gq + (size_t)(mt * 16 + l15) * DIM + k0);
#pragma unroll
        for (int nt = 0; nt < 4; ++nt)
            bf[nt] = *(const s16x8*)(wf +
                     ((size_t)((h * 4 + nt) * 16 + ks) * 64 + lane) * 8);
#pragma unroll
        for (int mt = 0; mt < 4; ++mt)
#pragma unroll
            for (int nt = 0; nt < 4; ++nt)
                acc[mt][nt] = mma(af[mt], bf[nt], acc[mt][nt]);
    }
#pragma unroll
    for (int nt = 0; nt < 4; ++nt) {
        float bqv = bq[h * 64 + nt * 16 + l15];
#pragma unroll
        for (int mt = 0; mt < 4; ++mt)
#pragma unroll
            for (int r = 0; r < 4; ++r)
                T[mt * 16 + l4 * 4 + r][nt * 16 + l15] = f2bf(acc[mt][nt][r] + bqv);
    }
    s16x8 qa[4][2], qb[4][2];
#pragma unroll
    for (int mt = 0; mt < 4; ++mt)
#pragma unroll
        for (int ks = 0; ks < 2; ++ks)
            qa[mt][ks] = *(const s16x8*)&T[mt * 16 + l15][ks * 32 + l4 * 8];
#pragma unroll
    for (int nt = 0; nt < 4; ++nt)
#pragma unroll
        for (int ks = 0; ks < 2; ++ks) {
            s16x8 v;
#pragma unroll
            for (int j = 0; j < 8; ++j)
                v[j] = (short)T[ks * 32 + l4 * 8 + j][nt * 16 + l15];
            qb[nt][ks] = v;
        }
    f32x4 Sc[4][4];
#pragma unroll
    for (int i = 0; i < 4; ++i)
#pragma unroll
        for (int j = 0; j < 4; ++j) Sc[i][j] = fz;
#pragma unroll
    for (int ks = 0; ks < 2; ++ks)
#pragma unroll
        for (int mt = 0; mt < 4; ++mt)
#pragma unroll
            for (int nt = 0; nt < 4; ++nt)
                Sc[mt][nt] = mma(qa[mt][ks], cb[nt][ks], Sc[mt][nt]);
#pragma unroll
    for (int mt = 0; mt < 4; ++mt)
#pragma unroll
        for (int r = 0; r < 4; ++r) {
            float m = fmaxf(fmaxf(Sc[mt][0][r], Sc[mt][1][r]),
                            fmaxf(Sc[mt][2][r], Sc[mt][3][r]));
            m = fmaxf(m, __shfl_xor(m, 1));
            m = fmaxf(m, __shfl_xor(m, 2));
            m = fmaxf(m, __shfl_xor(m, 4));
            m = fmaxf(m, __shfl_xor(m, 8));
            float e[4], s = 0.f;
#pragma unroll
            for (int nt = 0; nt < 4; ++nt) { e[nt] = __expf(SCALE * (Sc[mt][nt][r] - m)); s += e[nt]; }
            s += __shfl_xor(s, 1);
            s += __shfl_xor(s, 2);
            s += __shfl_xor(s, 4);
            s += __shfl_xor(s, 8);
            float inv = 1.f / s;
            int row = mt * 16 + l4 * 4 + r;
#pragma unroll
            for (int nt = 0; nt < 4; ++nt)
                T[row][nt * 16 + l15] = f2bf(e[nt] * inv);
        }
    s16x8 pa[4][2];
#pragma unroll
    for (int mt = 0; mt < 4; ++mt)
#pragma unroll
        for (int ks = 0; ks < 2; ++ks)
            pa[mt][ks] = *(const s16x8*)&T[mt * 16 + l15][ks * 32 + l4 * 8];
#pragma unroll
    for (int nt = 0; nt < 4; ++nt) {
        float m = -1e30f;
#pragma unroll
        for (int mt = 0; mt < 4; ++mt)
#pragma unroll
            for (int r = 0; r < 4; ++r) m = fmaxf(m, Sc[mt][nt][r]);
        m = fmaxf(m, __shfl_xor(m, 16));
        m = fmaxf(m, __shfl_xor(m, 32));
        float ee[4][4], s = 0.f;
#pragma unroll
        for (int mt = 0; mt < 4; ++mt)
#pragma unroll
            for (int r = 0; r < 4; ++r) { ee[mt][r] = __expf(SCALE * (Sc[mt][nt][r] - m)); s += ee[mt][r]; }
        s += __shfl_xor(s, 16);
        s += __shfl_xor(s, 32);
        float inv = 1.f / s;
        int krow = nt * 16 + l15;
#pragma unroll
        for (int mt = 0; mt < 4; ++mt)
#pragma unroll
            for (int r = 0; r < 4; ++r)
                T[krow][mt * 16 + l4 * 4 + r] = f2bf(ee[mt][r] * inv);
    }
    s16x8 p2a[4][2];
#pragma unroll
    for (int mt = 0; mt < 4; ++mt)
#pragma unroll
        for (int ks = 0; ks < 2; ++ks)
            p2a[mt][ks] = *(const s16x8*)&T[mt * 16 + l15][ks * 32 + l4 * 8];
    f32x4 O[4][4];
#pragma unroll
    for (int i = 0; i < 4; ++i)
#pragma unroll
        for (int j = 0; j < 4; ++j) O[i][j] = fz;
#pragma unroll
    for (int ks = 0; ks < 2; ++ks)
#pragma unroll
        for (int mt = 0; mt < 4; ++mt)
#pragma unroll
            for (int nt = 0; nt < 4; ++nt)
                O[mt][nt] = mma(pa[mt][ks], cb[nt][ks], O[mt][nt]);
    float* cO = out;
#pragma unroll
    for (int mt = 0; mt < 4; ++mt)
#pragma unroll
        for (int nt = 0; nt < 4; ++nt)
#pragma unroll
            for (int r = 0; r < 4; ++r) {
                int qrow = mt * 16 + l4 * 4 + r;
                cO[((size_t)b * SEQ + qrow) * (NH * 64) + h * 64 + nt * 16 + l15] = O[mt][nt][r];
            }
#pragma unroll
    for (int i = 0; i < 4; ++i)
#pragma unroll
        for (int j = 0; j < 4; ++j) O[i][j] = fz;
#pragma unroll
    for (int ks = 0; ks < 2; ++ks)
#pragma unroll
        for (int mt = 0; mt < 4; ++mt)
#pragma unroll
            for (int nt = 0; nt < 4; ++nt)
                O[mt][nt] = mma(p2a[mt][ks], qb[nt][ks], O[mt][nt]);
    float* qO = out + (size_t)NB * SEQ * NH * 64;
#pragma unroll
    for (int mt = 0; mt < 4; ++mt)
#pragma unroll
        for (int nt = 0; nt < 4; ++nt)
#pragma unroll
            for (int r = 0; r < 4; ++r) {
                int krow = mt * 16 + l4 * 4 + r;
                qO[((size_t)b * SEQ + krow) * (NH * 64) + h * 64 + nt * 16 + l15] = O[mt][nt][r];
            }
}

extern "C" void kernel_launch(void* const* d_in, const int* in_sizes, int n_in,
                              void* d_out, int out_size, void* d_ws, size_t ws_size,
                              hipStream_t stream) {
    const float* query   = (const float*)d_in[0];
    const float* context = (const float*)d_in[1];
    const float* Wq      = (const float*)d_in[2];
    const float* bq      = (const float*)d_in[3];
    const float* Wc      = (const float*)d_in[4];
    const float* bc      = (const float*)d_in[5];
    float* out = (float*)d_out;

    unsigned short* wfrag = (unsigned short*)d_ws;            // 1 MB
    unsigned short* pp    = wfrag + 524288;                   // 134.2 MB
    const size_t need = (524288 + (size_t)2 * NB * NH * 4096) * sizeof(unsigned short);

    prep_weights<<<256, 256, 0, stream>>>(Wq, Wc, wfrag);
    if (ws_size >= need) {
        proj_kernel<<<2048, 512, 0, stream>>>(query, context, bq, bc, wfrag, pp);
        tail_kernel<<<2048, 256, 0, stream>>>(pp, out);
    } else {
        coattn_fused<<<NB * 2, 256, 0, stream>>>(query, context, bq, bc, wfrag, out);
    }
}